// Round 1
// 579.506 us; speedup vs baseline: 1.0649x; 1.0649x over previous
//
#include <hip/hip_runtime.h>

// LinearAttention: b=16, n=4096, dim=512, H=8, D=64, inner=512. T=65536 tokens.
// I/O dtype: fp32 (per reference). Compute: bf16 MFMA, fp32 accumulate.
// ws layout (~73 MiB total):
//   wq_bf  [1536x512 bf16]  converted W_qkv
//   wo_bf  [ 512x512 bf16]  converted W_out
//   wsq    [65536x512 bf16] q' = act(x@Wq^T); overwritten in-place with attn
//   kvglob [128 x 64x80 f32] kv accumulator (atomicAdd), col e=64 = ksum
//   kvt    [128 x 80x64 bf16] kv transposed [e][d]; row 64 = ksum

typedef unsigned short u16;
typedef u16 u16x4 __attribute__((ext_vector_type(4)));
typedef u16 u16x8 __attribute__((ext_vector_type(8)));
typedef __bf16 bf16x8 __attribute__((ext_vector_type(8)));
typedef float f32x4 __attribute__((ext_vector_type(4)));

__device__ __forceinline__ float bf2f(u16 x) {
    union { unsigned u; float f; } t; t.u = ((unsigned)x) << 16; return t.f;
}
__device__ __forceinline__ u16 f2bf(float f) {
    union { float f; unsigned u; } t; t.f = f;
    unsigned r = t.u + 0x7fffu + ((t.u >> 16) & 1u);   // RNE
    return (u16)(r >> 16);
}
__device__ __forceinline__ float act_fn(float v) {     // 1 + elu
    return v > 0.0f ? v + 1.0f : __expf(v);
}

// ---------------------------------------------------------------------------
// convert W_qkv (786432 f32) and W_out (262144 f32) to bf16. 1024x256 thr x4 el.
// ---------------------------------------------------------------------------
__global__ __launch_bounds__(256) void convert_w(const float* __restrict__ Wqkv,
                                                 const float* __restrict__ Wout,
                                                 u16* __restrict__ wq_bf,
                                                 u16* __restrict__ wo_bf)
{
    const size_t j = ((size_t)blockIdx.x * 256 + threadIdx.x) * 4;
    const float* src; u16* dst; size_t off;
    if (j < 786432) { src = Wqkv; dst = wq_bf; off = j; }
    else            { src = Wout; dst = wo_bf; off = j - 786432; }
    f32x4 v = *(const f32x4*)&src[off];
    u16x4 o = { f2bf(v[0]), f2bf(v[1]), f2bf(v[2]), f2bf(v[3]) };
    *(u16x4*)&dst[off] = o;
}

// zero the 128*5120-float kv accumulator (atomics land here). grid 640x256x4.
__global__ __launch_bounds__(256) void zero_kv(float* __restrict__ p)
{
    const size_t i = ((size_t)blockIdx.x * 256 + threadIdx.x) * 4;
    f32x4 z = { 0.f, 0.f, 0.f, 0.f };
    *(f32x4*)&p[i] = z;
}

// ---------------------------------------------------------------------------
// gemm_q: wsq[t][c] = act( sum_k x[t][k] * Wq[c][k] ), c in [0,512).
// A fp32 (converted in staging), B bf16 rows 0..511 of wq_bf, K=512.
// 128x128 tile, BK=32, 256 thr (2x2 wave quadrants) — verified m92 pattern.
// ---------------------------------------------------------------------------
__global__ __launch_bounds__(256) void gemm_q(const float* __restrict__ A,
                                              const u16* __restrict__ Bw,
                                              u16* __restrict__ C)
{
    __shared__ u16 As[128 * 32];
    __shared__ u16 Bs[128 * 32];
    const int tid  = threadIdx.x;
    const int wave = tid >> 6, lane = tid & 63;
    const size_t row0 = (size_t)blockIdx.x * 128;
    const int    col0 = blockIdx.y * 128;
    const int wr = (wave >> 1) * 64, wc = (wave & 1) * 64;
    const int frow = lane & 15, quad = lane >> 4;

    f32x4 acc[4][4] = {};

    const int j0 = tid, j1 = tid + 256;
    const int r0 = j0 >> 2, c0 = (j0 & 3) * 8;
    const int r1 = j1 >> 2, c1 = (j1 & 3) * 8;
    const float* gA0 = A + (row0 + r0) * 512 + c0;
    const float* gA1 = A + (row0 + r1) * 512 + c1;
    const u16* gB0 = Bw + (size_t)(col0 + r0) * 512 + c0;
    const u16* gB1 = Bw + (size_t)(col0 + r1) * 512 + c1;

    for (int k0 = 0; k0 < 512; k0 += 32) {
        f32x4 a0l = *(const f32x4*)(gA0 + k0);
        f32x4 a0h = *(const f32x4*)(gA0 + k0 + 4);
        f32x4 a1l = *(const f32x4*)(gA1 + k0);
        f32x4 a1h = *(const f32x4*)(gA1 + k0 + 4);
        u16x8 b0 = *(const u16x8*)(gB0 + k0);
        u16x8 b1 = *(const u16x8*)(gB1 + k0);
        u16x8 a0 = { f2bf(a0l[0]), f2bf(a0l[1]), f2bf(a0l[2]), f2bf(a0l[3]),
                     f2bf(a0h[0]), f2bf(a0h[1]), f2bf(a0h[2]), f2bf(a0h[3]) };
        u16x8 a1 = { f2bf(a1l[0]), f2bf(a1l[1]), f2bf(a1l[2]), f2bf(a1l[3]),
                     f2bf(a1h[0]), f2bf(a1h[1]), f2bf(a1h[2]), f2bf(a1h[3]) };
        __syncthreads();
        *(u16x8*)&As[j0 * 8] = a0;
        *(u16x8*)&As[j1 * 8] = a1;
        *(u16x8*)&Bs[j0 * 8] = b0;
        *(u16x8*)&Bs[j1 * 8] = b1;
        __syncthreads();

        bf16x8 af[4], bfr[4];
#pragma unroll
        for (int mi = 0; mi < 4; ++mi)
            af[mi] = *(const bf16x8*)&As[(wr + mi * 16 + frow) * 32 + quad * 8];
#pragma unroll
        for (int ni = 0; ni < 4; ++ni)
            bfr[ni] = *(const bf16x8*)&Bs[(wc + ni * 16 + frow) * 32 + quad * 8];
#pragma unroll
        for (int mi = 0; mi < 4; ++mi)
#pragma unroll
            for (int ni = 0; ni < 4; ++ni)
                acc[mi][ni] = __builtin_amdgcn_mfma_f32_16x16x32_bf16(af[mi], bfr[ni], acc[mi][ni], 0, 0, 0);
    }

    // C/D layout: col = lane&15, row = quad*4 + reg  [measured m89/m91]
#pragma unroll
    for (int mi = 0; mi < 4; ++mi) {
#pragma unroll
        for (int ni = 0; ni < 4; ++ni) {
            const int c = col0 + wc + ni * 16 + frow;
            const size_t rbase = row0 + wr + mi * 16 + quad * 4;
#pragma unroll
            for (int reg = 0; reg < 4; ++reg)
                C[(rbase + reg) * 512 + c] = f2bf(act_fn(acc[mi][ni][reg]));
        }
    }
}

// ---------------------------------------------------------------------------
// kv_all: one block per (b, 128-token tile), 512 thr (8 waves), ALL 8 heads.
// x tile converted fp32->bf16 ONCE into swizzled LDS (was 8x, once per head).
// Per head: k|v = x@Wkv_h^T (W chunk staged to LDS, reg-prefetched), transpose
// via KT/VT (time-shared with Bs region), kv[d][e] += KT@VT^T in 2 token
// halves (VT row 64 = ones => col e=64 = ksum). Partials atomicAdd to kvglob.
// LDS: As 131072 + max(Bs 18432, KT 9216 + VT 20736-9216) = 151808 B.
// ---------------------------------------------------------------------------
__global__ __launch_bounds__(512, 2) void kv_all(const float* __restrict__ x,
                                                 const u16* __restrict__ wbf,
                                                 float* __restrict__ kvglob)
{
    __shared__ __align__(16) char SM[151808];
    u16* Bs = (u16*)(SM + 131072);          // [128][72] head-W chunk (K=64)
    u16* KT = (u16*)(SM + 131072);          // [64][72]  k^T (overlays Bs)
    u16* VT = (u16*)(SM + 131072 + 9216);   // [80][72]  v^T; rows 64..79 static

    const int b = blockIdx.x, tile = blockIdx.y;
    const int tid = threadIdx.x;
    const int wave = tid >> 6, lane = tid & 63;
    const int frow = lane & 15, quad = lane >> 4;

    // ---- stage x tile (128 tok x 512 K) fp32 -> bf16, swizzle ^((tok&7)<<4)
    {
        const size_t trow = (size_t)b * 4096 + (size_t)tile * 128;
        for (int u = tid; u < 8192; u += 512) {
            const int tok = u >> 6, kc = (u & 63) * 8;
            const float* g = x + (trow + tok) * 512 + kc;
            f32x4 lo = *(const f32x4*)g;
            f32x4 hi = *(const f32x4*)(g + 4);
            u16x8 o = { f2bf(lo[0]), f2bf(lo[1]), f2bf(lo[2]), f2bf(lo[3]),
                        f2bf(hi[0]), f2bf(hi[1]), f2bf(hi[2]), f2bf(hi[3]) };
            const unsigned byte = (unsigned)(tok * 1024 + kc * 2) ^ ((unsigned)(tok & 7) << 4);
            *(u16x8*)(SM + byte) = o;
        }
        // VT rows 64..79: row 64 = 1.0 (ksum via ones trick), rest 0.
        // These rows sit past the Bs overlay (byte 18432+) — written once.
        for (int i = tid; i < 16 * 72; i += 512)
            VT[64 * 72 + i] = (i < 72) ? (u16)0x3F80 : (u16)0;
    }

    const int mt0 = (wave & 3) * 2;        // wave's 2 token tiles (16 tok each)
    const int nt0 = (wave >> 2) * 4;       // wave's 4 col tiles (cols 0..63=k, 64..127=v)
    const bool is_k = (wave < 4);

    // W-chunk staging: thread owns one k-row unit and one v-row unit.
    const int srow = tid >> 3;             // 0..63
    const int skc  = (tid & 7) * 8;        // 0..56
    // prefetch chunk (h=0, kb=0) into regs (T14: issue early, write late)
    const u16* wk0 = wbf + ((size_t)512 + (size_t)srow) * 512 + skc;
    u16x8 breg0 = *(const u16x8*)(wk0);
    u16x8 breg1 = *(const u16x8*)(wk0 + 512 * 512);

    for (int h = 0; h < 8; ++h) {
        f32x4 cacc[2][4] = {};
        f32x4 kvacc[5] = {};

        for (int kb = 0; kb < 8; ++kb) {
            __syncthreads();               // prev Bs/KT/VT readers done
            *(u16x8*)&Bs[srow * 72 + skc] = breg0;
            *(u16x8*)&Bs[(srow + 64) * 72 + skc] = breg1;
            __syncthreads();

            // prefetch next chunk while this chunk's MFMAs run
            if (h * 8 + kb < 63) {
                const int nh  = (kb < 7) ? h : h + 1;
                const int nkb = (kb < 7) ? kb + 1 : 0;
                const u16* pk = wbf + ((size_t)512 + (size_t)nh * 64 + (size_t)srow) * 512
                                + (size_t)nkb * 64 + skc;
                breg0 = *(const u16x8*)(pk);
                breg1 = *(const u16x8*)(pk + 512 * 512);
            }

#pragma unroll
            for (int k2 = 0; k2 < 2; ++k2) {
                const int kA = kb * 64 + k2 * 32 + quad * 8;
                bf16x8 af[2], bfr[4];
#pragma unroll
                for (int mi = 0; mi < 2; ++mi) {
                    const int tok = (mt0 + mi) * 16 + frow;
                    const unsigned byte = (unsigned)(tok * 1024 + kA * 2)
                                          ^ ((unsigned)(tok & 7) << 4);
                    af[mi] = *(const bf16x8*)(SM + byte);
                }
#pragma unroll
                for (int ni = 0; ni < 4; ++ni) {
                    const int cl = (nt0 + ni) * 16 + frow;
                    bfr[ni] = *(const bf16x8*)&Bs[cl * 72 + k2 * 32 + quad * 8];
                }
#pragma unroll
                for (int mi = 0; mi < 2; ++mi)
#pragma unroll
                    for (int ni = 0; ni < 4; ++ni)
                        cacc[mi][ni] = __builtin_amdgcn_mfma_f32_16x16x32_bf16(
                            af[mi], bfr[ni], cacc[mi][ni], 0, 0, 0);
            }
        }

        // transpose C -> KT/VT and accumulate kv, in 2 token halves of 64
#pragma unroll
        for (int half = 0; half < 2; ++half) {
            __syncthreads();               // prior Bs readers / outer readers done
            if (((wave & 3) >> 1) == half) {
#pragma unroll
                for (int mi = 0; mi < 2; ++mi) {
                    const int nh0 = (mt0 + mi) * 16 + quad * 4 - half * 64;  // 0..60
#pragma unroll
                    for (int ni = 0; ni < 4; ++ni) {
                        const int cl = (nt0 + ni) * 16 + frow;               // 0..127
                        u16x4 o;
#pragma unroll
                        for (int reg = 0; reg < 4; ++reg) {
                            float v = cacc[mi][ni][reg];
                            if (is_k) v = act_fn(v);
                            o[reg] = f2bf(v);
                        }
                        if (is_k) *(u16x4*)&KT[cl * 72 + nh0] = o;
                        else      *(u16x4*)&VT[(cl - 64) * 72 + nh0] = o;
                    }
                }
            }
            __syncthreads();
            if (wave < 4) {                // d-tile = wave; kv[d][e] += KT@VT^T
#pragma unroll
                for (int c = 0; c < 2; ++c) {
                    bf16x8 af2 = *(const bf16x8*)&KT[(wave * 16 + frow) * 72 + c * 32 + quad * 8];
#pragma unroll
                    for (int et = 0; et < 5; ++et) {
                        bf16x8 bf2 = *(const bf16x8*)&VT[(et * 16 + frow) * 72 + c * 32 + quad * 8];
                        kvacc[et] = __builtin_amdgcn_mfma_f32_16x16x32_bf16(
                            af2, bf2, kvacc[et], 0, 0, 0);
                    }
                }
            }
        }

        if (wave < 4) {
            float* dst = kvglob + (size_t)(b * 8 + h) * 5120;
#pragma unroll
            for (int et = 0; et < 5; ++et) {
                const int e = et * 16 + frow;
                if (e <= 64) {
#pragma unroll
                    for (int reg = 0; reg < 4; ++reg) {
                        const int d = wave * 16 + quad * 4 + reg;
                        atomicAdd(&dst[d * 80 + e], kvacc[et][reg]);
                    }
                }
            }
        }
    }
}

// kvt[bh][e][d] bf16: transpose of kvglob[bh][d][e]; e rows 65..79 zero.
__global__ __launch_bounds__(256) void reduce_kvt(const float* __restrict__ kvglob,
                                                  u16* __restrict__ kvt)
{
    const int bh = blockIdx.x, tid = threadIdx.x;
    for (int i = tid; i < 5120; i += 256) {
        const int e = i >> 6, d = i & 63;
        kvt[(size_t)bh * 5120 + i] =
            (e < 65) ? f2bf(kvglob[(size_t)bh * 5120 + d * 80 + e]) : (u16)0;
    }
}

// ---------------------------------------------------------------------------
// apply_attn: attnT[e][tok] = sum_d kvt[e][d] * q'[tok][d] by MFMA; row e=64
// gives denominator (shfl-broadcast); attn = num*z overwrites q' IN PLACE
// (per head: reads of head h's cols complete before its writes; blocks/waves
// own disjoint tokens). No LDS.
// ---------------------------------------------------------------------------
__global__ __launch_bounds__(256) void apply_attn(u16* __restrict__ qio,
                                                  const u16* __restrict__ kvt)
{
    const int blk = blockIdx.x;               // 512 blocks x 128 tokens
    const size_t t0 = (size_t)blk * 128;
    const int bb = blk >> 5;                  // batch = 32 blocks
    const int tid = threadIdx.x, wave = tid >> 6, lane = tid & 63;
    const int frow = lane & 15, quad = lane >> 4;
    const int wt = wave * 32;                 // wave owns 32 tokens

    for (int h = 0; h < 8; ++h) {
        const u16* kvh = kvt + (size_t)(bb * 8 + h) * 5120;
        f32x4 acc[5][2] = {};                 // mi: e-tile(80), ni: tok-tile(32)
#pragma unroll
        for (int kc = 0; kc < 2; ++kc) {      // d = kc*32 + quad*8 + j
            bf16x8 bfr[2];
#pragma unroll
            for (int ni = 0; ni < 2; ++ni)
                bfr[ni] = *(const bf16x8*)&qio[(t0 + wt + ni * 16 + frow) * 512 + h * 64 + kc * 32 + quad * 8];
#pragma unroll
            for (int mi = 0; mi < 5; ++mi) {
                bf16x8 afr = *(const bf16x8*)&kvh[(mi * 16 + frow) * 64 + kc * 32 + quad * 8];
#pragma unroll
                for (int ni = 0; ni < 2; ++ni)
                    acc[mi][ni] = __builtin_amdgcn_mfma_f32_16x16x32_bf16(afr, bfr[ni], acc[mi][ni], 0, 0, 0);
            }
        }
#pragma unroll
        for (int ni = 0; ni < 2; ++ni) {
            // den(tok) sits in row e=64: lanes quad==0, reg 0, col=tok&15
            const float den = __shfl(acc[4][ni][0], frow, 64);
            const float z = 1.0f / fmaxf(den, 1e-4f);
            const size_t tok = t0 + wt + ni * 16 + frow;
#pragma unroll
            for (int mi = 0; mi < 4; ++mi) {
                u16x4 o;
#pragma unroll
                for (int reg = 0; reg < 4; ++reg) o[reg] = f2bf(acc[mi][ni][reg] * z);
                *(u16x4*)&qio[tok * 512 + h * 64 + mi * 16 + quad * 4] = o;
            }
        }
    }
}

// ---------------------------------------------------------------------------
// gemm_out: out[t][c] (fp32) = sum_i attn[t][i]*Wout[c][i] + bias[c].
// A bf16 (wsq), B bf16 (wo_bf), C fp32.
// ---------------------------------------------------------------------------
__global__ __launch_bounds__(256) void gemm_out(const u16* __restrict__ A,
                                                const u16* __restrict__ Bw,
                                                float* __restrict__ C,
                                                const float* __restrict__ bias)
{
    __shared__ u16 As[128 * 32];
    __shared__ u16 Bs[128 * 32];
    const int tid  = threadIdx.x;
    const int wave = tid >> 6, lane = tid & 63;
    const size_t row0 = (size_t)blockIdx.x * 128;
    const int    col0 = blockIdx.y * 128;
    const int wr = (wave >> 1) * 64, wc = (wave & 1) * 64;
    const int frow = lane & 15, quad = lane >> 4;

    f32x4 acc[4][4] = {};

    const int j0 = tid, j1 = tid + 256;
    const int r0 = j0 >> 2, c0 = (j0 & 3) * 8;
    const int r1 = j1 >> 2, c1 = (j1 & 3) * 8;
    const u16* gA0 = A + (row0 + r0) * 512 + c0;
    const u16* gA1 = A + (row0 + r1) * 512 + c1;
    const u16* gB0 = Bw + (size_t)(col0 + r0) * 512 + c0;
    const u16* gB1 = Bw + (size_t)(col0 + r1) * 512 + c1;

    for (int k0 = 0; k0 < 512; k0 += 32) {
        u16x8 a0 = *(const u16x8*)(gA0 + k0);
        u16x8 a1 = *(const u16x8*)(gA1 + k0);
        u16x8 b0 = *(const u16x8*)(gB0 + k0);
        u16x8 b1 = *(const u16x8*)(gB1 + k0);
        __syncthreads();
        *(u16x8*)&As[j0 * 8] = a0;
        *(u16x8*)&As[j1 * 8] = a1;
        *(u16x8*)&Bs[j0 * 8] = b0;
        *(u16x8*)&Bs[j1 * 8] = b1;
        __syncthreads();

        bf16x8 af[4], bfr[4];
#pragma unroll
        for (int mi = 0; mi < 4; ++mi)
            af[mi] = *(const bf16x8*)&As[(wr + mi * 16 + frow) * 32 + quad * 8];
#pragma unroll
        for (int ni = 0; ni < 4; ++ni)
            bfr[ni] = *(const bf16x8*)&Bs[(wc + ni * 16 + frow) * 32 + quad * 8];
#pragma unroll
        for (int mi = 0; mi < 4; ++mi)
#pragma unroll
            for (int ni = 0; ni < 4; ++ni)
                acc[mi][ni] = __builtin_amdgcn_mfma_f32_16x16x32_bf16(af[mi], bfr[ni], acc[mi][ni], 0, 0, 0);
    }

#pragma unroll
    for (int mi = 0; mi < 4; ++mi) {
#pragma unroll
        for (int ni = 0; ni < 4; ++ni) {
            const int c = col0 + wc + ni * 16 + frow;
            const float bv = bias[c];
            const size_t rbase = row0 + wr + mi * 16 + quad * 4;
#pragma unroll
            for (int reg = 0; reg < 4; ++reg)
                C[(rbase + reg) * 512 + c] = acc[mi][ni][reg] + bv;
        }
    }
}

extern "C" void kernel_launch(void* const* d_in, const int* in_sizes, int n_in,
                              void* d_out, int out_size, void* d_ws, size_t ws_size,
                              hipStream_t stream)
{
    const float* x    = (const float*)d_in[0];   // [65536, 512] fp32
    const float* Wqkv = (const float*)d_in[1];   // [1536, 512]  fp32
    const float* Wout = (const float*)d_in[2];   // [512, 512]   fp32
    const float* bout = (const float*)d_in[3];   // [512]        fp32
    float* out = (float*)d_out;                  // [65536, 512] fp32
    char* ws = (char*)d_ws;

    u16*   wq_bf  = (u16*)ws;                    //  1,572,864 B
    u16*   wo_bf  = (u16*)(ws + 1572864ull);     //    524,288 B
    u16*   wsq    = (u16*)(ws + 2097152ull);     // 67,108,864 B
    float* kvglob = (float*)(ws + 69206016ull);  //  2,621,440 B
    u16*   kvt    = (u16*)(ws + 71827456ull);    //  1,310,720 B -> end 73,138,176

    // 0) weights -> bf16; zero kv accumulator
    convert_w<<<1024, 256, 0, stream>>>(Wqkv, Wout, wq_bf, wo_bf);
    zero_kv<<<640, 256, 0, stream>>>(kvglob);
    // 1) q' = act(x @ Wq^T) -> wsq (bf16)
    gemm_q<<<dim3(512, 4), 256, 0, stream>>>(x, wq_bf, wsq);
    // 2) fused k/v + kv/ksum for all heads, x staged+converted once per tile
    kv_all<<<dim3(16, 32), 512, 0, stream>>>(x, wq_bf, kvglob);
    // 3) transpose -> bf16 kvt (row e=64 = ksum)
    reduce_kvt<<<128, 256, 0, stream>>>(kvglob, kvt);
    // 4) attention apply, in-place on wsq (q' -> attn)
    apply_attn<<<512, 256, 0, stream>>>(wsq, kvt);
    // 5) out = attn @ Wout^T + b_out -> d_out (fp32)
    gemm_out<<<dim3(512, 4), 256, 0, stream>>>(wsq, wo_bf, out, bout);
}

// Round 2
// 557.102 us; speedup vs baseline: 1.1077x; 1.0402x over previous
//
#include <hip/hip_runtime.h>

// LinearAttention: b=16, n=4096, dim=512, H=8, D=64, inner=512. T=65536 tokens.
// I/O dtype: fp32 (per reference). Compute: bf16 MFMA, fp32 accumulate.
// ws layout (~133.8 MiB):
//   wq_bf  [1536x512 bf16]  converted W_qkv
//   wo_bf  [ 512x512 bf16]  converted W_out
//   wsq    [65536x512 bf16] q' = act(x@Wq^T); overwritten in-place with attn
//   xb     [65536x512 bf16] x converted once (kills all hot-loop f2bf)
//   kvglob [128 x 64x80 f32] kv accumulator (atomicAdd), col e=64 = ksum
//   kvt    [128 x 80x64 bf16] kv transposed [e][d]; row 64 = ksum

typedef unsigned short u16;
typedef u16 u16x4 __attribute__((ext_vector_type(4)));
typedef u16 u16x8 __attribute__((ext_vector_type(8)));
typedef __bf16 bf16x8 __attribute__((ext_vector_type(8)));
typedef float f32x4 __attribute__((ext_vector_type(4)));

__device__ __forceinline__ u16 f2bf(float f) {
    union { float f; unsigned u; } t; t.f = f;
    unsigned r = t.u + 0x7fffu + ((t.u >> 16) & 1u);   // RNE
    return (u16)(r >> 16);
}
__device__ __forceinline__ float act_fn(float v) {     // 1 + elu
    return v > 0.0f ? v + 1.0f : __expf(v);
}
__device__ __forceinline__ void cvt8(const float* __restrict__ s, u16* __restrict__ d) {
    f32x4 lo = *(const f32x4*)s;
    f32x4 hi = *(const f32x4*)(s + 4);
    u16x8 o = { f2bf(lo[0]), f2bf(lo[1]), f2bf(lo[2]), f2bf(lo[3]),
                f2bf(hi[0]), f2bf(hi[1]), f2bf(hi[2]), f2bf(hi[3]) };
    *(u16x8*)d = o;
}
// async global->LDS, 16B per lane. LDS dest = wave-uniform base + lane*16.
__device__ __forceinline__ void gld16(const u16* g, u16* l) {
    __builtin_amdgcn_global_load_lds(
        (__attribute__((address_space(1))) const void*)g,
        (__attribute__((address_space(3))) void*)l, 16, 0, 0);
}

// ---------------------------------------------------------------------------
// convert_all: x (4,194,304 x8 units) -> xb ; W_qkv (98,304) -> wq_bf ;
// W_out (32,768) -> wo_bf ; zero kvglob (81,920 x8 f32). 17,216 x 256 exact.
// ---------------------------------------------------------------------------
__global__ __launch_bounds__(256) void convert_all(const float* __restrict__ x,
                                                   const float* __restrict__ Wqkv,
                                                   const float* __restrict__ Wout,
                                                   u16* __restrict__ xb,
                                                   u16* __restrict__ wq,
                                                   u16* __restrict__ wo,
                                                   float* __restrict__ kvg)
{
    size_t u = (size_t)blockIdx.x * 256 + threadIdx.x;
    if (u < 4194304ull) {
        cvt8(x + u * 8, xb + u * 8);
    } else if (u < 4292608ull) {
        u -= 4194304ull; cvt8(Wqkv + u * 8, wq + u * 8);
    } else if (u < 4325376ull) {
        u -= 4292608ull; cvt8(Wout + u * 8, wo + u * 8);
    } else {
        u -= 4325376ull;
        f32x4 z = { 0.f, 0.f, 0.f, 0.f };
        *(f32x4*)&kvg[u * 8] = z;
        *(f32x4*)&kvg[u * 8 + 4] = z;
    }
}

// ---------------------------------------------------------------------------
// gemm_q: wsq[t][c] = act( sum_k xb[t][k] * Wq[c][k] ). All-bf16, m97-style
// global_load_lds staging. 128x128 tile, BK=32, 256 thr.
// ---------------------------------------------------------------------------
__global__ __launch_bounds__(256) void gemm_q(const u16* __restrict__ A,
                                              const u16* __restrict__ Bw,
                                              u16* __restrict__ C)
{
    __shared__ u16 As[128 * 32];
    __shared__ u16 Bs[128 * 32];
    const int tid  = threadIdx.x;
    const int wave = tid >> 6, lane = tid & 63;
    const size_t row0 = (size_t)blockIdx.x * 128;
    const int    col0 = blockIdx.y * 128;
    const int wr = (wave >> 1) * 64, wc = (wave & 1) * 64;
    const int frow = lane & 15, quad = lane >> 4;

    f32x4 acc[4][4] = {};

    // staging: chunk = issue*256 + wave*64 + lane ; row = ch>>2, col = (ch&3)*8
    const int ch0 = wave * 64 + lane, ch1 = 256 + ch0;
    const int r0 = ch0 >> 2, c0 = (ch0 & 3) * 8;
    const int r1 = ch1 >> 2, c1 = (ch1 & 3) * 8;
    const u16* gA0 = A + (row0 + r0) * 512 + c0;
    const u16* gA1 = A + (row0 + r1) * 512 + c1;
    const u16* gB0 = Bw + (size_t)(col0 + r0) * 512 + c0;
    const u16* gB1 = Bw + (size_t)(col0 + r1) * 512 + c1;
    u16* lA0 = As + wave * 512;  u16* lA1 = As + 2048 + wave * 512;
    u16* lB0 = Bs + wave * 512;  u16* lB1 = Bs + 2048 + wave * 512;

    for (int k0 = 0; k0 < 512; k0 += 32) {
        __syncthreads();
        gld16(gA0 + k0, lA0); gld16(gA1 + k0, lA1);
        gld16(gB0 + k0, lB0); gld16(gB1 + k0, lB1);
        __syncthreads();

        bf16x8 af[4], bfr[4];
#pragma unroll
        for (int mi = 0; mi < 4; ++mi)
            af[mi] = *(const bf16x8*)&As[(wr + mi * 16 + frow) * 32 + quad * 8];
#pragma unroll
        for (int ni = 0; ni < 4; ++ni)
            bfr[ni] = *(const bf16x8*)&Bs[(wc + ni * 16 + frow) * 32 + quad * 8];
#pragma unroll
        for (int mi = 0; mi < 4; ++mi)
#pragma unroll
            for (int ni = 0; ni < 4; ++ni)
                acc[mi][ni] = __builtin_amdgcn_mfma_f32_16x16x32_bf16(af[mi], bfr[ni], acc[mi][ni], 0, 0, 0);
    }

    // C/D layout: col = lane&15, row = quad*4 + reg  [measured m89/m91]
#pragma unroll
    for (int mi = 0; mi < 4; ++mi) {
#pragma unroll
        for (int ni = 0; ni < 4; ++ni) {
            const int c = col0 + wc + ni * 16 + frow;
            const size_t rbase = row0 + wr + mi * 16 + quad * 4;
#pragma unroll
            for (int reg = 0; reg < 4; ++reg)
                C[(rbase + reg) * 512 + c] = f2bf(act_fn(acc[mi][ni][reg]));
        }
    }
}

// ---------------------------------------------------------------------------
// kv_head: grid (head=8, tile=512), 256 thr, 37 KB LDS -> ~4 blocks/CU.
// C[128 tok][128 col] = xb_tile @ Wkv_head^T (cols 0..63 = k, 64..127 = v),
// global_load_lds staging. Epilogue: act on k, transpose to KT/VT in two
// 64-token halves, kv[d][e] += KT@VT^T (VT row 64 = ones -> e=64 col = ksum),
// atomicAdd into kvglob[b*8+h]. x re-read 8x across heads but L3-resident.
// ---------------------------------------------------------------------------
__global__ __launch_bounds__(256) void kv_head(const u16* __restrict__ xb,
                                               const u16* __restrict__ wbf,
                                               float* __restrict__ kvglob)
{
    __shared__ u16 As[128 * 32];
    __shared__ u16 Bs[128 * 32];
    __shared__ u16 KT[64 * 72];    // k^T [d][tok_half]
    __shared__ u16 VT[80 * 72];    // v^T [e][tok_half]; row 64 = ones
    const int head = blockIdx.x, tile = blockIdx.y;
    const int b = tile >> 5;
    const size_t row0 = (size_t)tile * 128;
    const int tid = threadIdx.x, wave = tid >> 6, lane = tid & 63;
    const int frow = lane & 15, quad = lane >> 4;
    const int wr = (wave >> 1) * 64, wc = (wave & 1) * 64;

    // VT rows 64..79: row 64 cols 0..63 = 1.0, rest 0. Written once.
    for (int i = tid; i < 16 * 72; i += 256)
        VT[64 * 72 + i] = (i < 64) ? (u16)0x3F80 : (u16)0;

    f32x4 cacc[4][4] = {};

    const int ch0 = wave * 64 + lane, ch1 = 256 + ch0;
    const int r0 = ch0 >> 2, c0 = (ch0 & 3) * 8;
    const int r1 = ch1 >> 2, c1 = (ch1 & 3) * 8;
    const u16* gA0 = xb + (row0 + r0) * 512 + c0;
    const u16* gA1 = xb + (row0 + r1) * 512 + c1;
    // W row for local col r: k -> 512 + h*64 + r ; v -> 1024 + h*64 + (r-64)
    const size_t wrow0 = (size_t)((r0 < 64 ? 512 : 960) + head * 64 + r0);
    const size_t wrow1 = (size_t)((r1 < 64 ? 512 : 960) + head * 64 + r1);
    const u16* gB0 = wbf + wrow0 * 512 + c0;
    const u16* gB1 = wbf + wrow1 * 512 + c1;
    u16* lA0 = As + wave * 512;  u16* lA1 = As + 2048 + wave * 512;
    u16* lB0 = Bs + wave * 512;  u16* lB1 = Bs + 2048 + wave * 512;

    for (int k0 = 0; k0 < 512; k0 += 32) {
        __syncthreads();
        gld16(gA0 + k0, lA0); gld16(gA1 + k0, lA1);
        gld16(gB0 + k0, lB0); gld16(gB1 + k0, lB1);
        __syncthreads();

        bf16x8 af[4], bfr[4];
#pragma unroll
        for (int mi = 0; mi < 4; ++mi)
            af[mi] = *(const bf16x8*)&As[(wr + mi * 16 + frow) * 32 + quad * 8];
#pragma unroll
        for (int ni = 0; ni < 4; ++ni)
            bfr[ni] = *(const bf16x8*)&Bs[(wc + ni * 16 + frow) * 32 + quad * 8];
#pragma unroll
        for (int mi = 0; mi < 4; ++mi)
#pragma unroll
            for (int ni = 0; ni < 4; ++ni)
                cacc[mi][ni] = __builtin_amdgcn_mfma_f32_16x16x32_bf16(af[mi], bfr[ni], cacc[mi][ni], 0, 0, 0);
    }

    const bool is_k = (wc == 0);
    f32x4 kvacc[5] = {};   // e-tiles; d = wave*16 + quad*4 + reg

#pragma unroll
    for (int half = 0; half < 2; ++half) {
        __syncthreads();               // prior KT/VT readers done
        if ((wave >> 1) == half) {     // this wave's tokens belong to this half
#pragma unroll
            for (int mi = 0; mi < 4; ++mi) {
                const int n0 = wr + mi * 16 + quad * 4 - half * 64;   // 0..60
#pragma unroll
                for (int ni = 0; ni < 4; ++ni) {
                    const int cl = wc + ni * 16 + frow;               // 0..127
                    u16x4 o;
#pragma unroll
                    for (int reg = 0; reg < 4; ++reg) {
                        float v = cacc[mi][ni][reg];
                        if (is_k) v = act_fn(v);
                        o[reg] = f2bf(v);
                    }
                    if (is_k) *(u16x4*)&KT[cl * 72 + n0] = o;
                    else      *(u16x4*)&VT[(cl - 64) * 72 + n0] = o;
                }
            }
        }
        __syncthreads();
        // kv[d][e] += KT@VT^T over this half's 64 tokens (2 K-chunks of 32)
#pragma unroll
        for (int c = 0; c < 2; ++c) {
            bf16x8 af2 = *(const bf16x8*)&KT[(wave * 16 + frow) * 72 + c * 32 + quad * 8];
#pragma unroll
            for (int et = 0; et < 5; ++et) {
                bf16x8 bf2 = *(const bf16x8*)&VT[(et * 16 + frow) * 72 + c * 32 + quad * 8];
                kvacc[et] = __builtin_amdgcn_mfma_f32_16x16x32_bf16(af2, bf2, kvacc[et], 0, 0, 0);
            }
        }
    }

    float* dst = kvglob + (size_t)(b * 8 + head) * 5120;
#pragma unroll
    for (int et = 0; et < 5; ++et) {
        const int e = et * 16 + frow;
        if (e <= 64) {
#pragma unroll
            for (int reg = 0; reg < 4; ++reg) {
                const int d = wave * 16 + quad * 4 + reg;
                atomicAdd(&dst[d * 80 + e], kvacc[et][reg]);
            }
        }
    }
}

// kvt[bh][e][d] bf16: transpose of kvglob[bh][d][e]; e rows 65..79 zero.
__global__ __launch_bounds__(256) void reduce_kvt(const float* __restrict__ kvglob,
                                                  u16* __restrict__ kvt)
{
    const int bh = blockIdx.x, tid = threadIdx.x;
    for (int i = tid; i < 5120; i += 256) {
        const int e = i >> 6, d = i & 63;
        kvt[(size_t)bh * 5120 + i] =
            (e < 65) ? f2bf(kvglob[(size_t)bh * 5120 + d * 80 + e]) : (u16)0;
    }
}

// ---------------------------------------------------------------------------
// apply_attn: attnT[e][tok] = sum_d kvt[e][d] * q'[tok][d] by MFMA; row e=64
// gives denominator (shfl-broadcast); attn = num*z overwrites q' IN PLACE.
// Grid (512 token-blocks x 4 head-pairs) -> 2048 blocks, 32 waves/CU.
// In-place safe: blocks touch disjoint (token, col) regions; within a wave,
// head-h reads complete (waitcnt) before head-h writes issue.
// ---------------------------------------------------------------------------
__global__ __launch_bounds__(256) void apply_attn(u16* __restrict__ qio,
                                                  const u16* __restrict__ kvt)
{
    const int blk = blockIdx.x;               // 512 blocks x 128 tokens
    const size_t t0 = (size_t)blk * 128;
    const int bb = blk >> 5;                  // batch = 32 blocks
    const int tid = threadIdx.x, wave = tid >> 6, lane = tid & 63;
    const int frow = lane & 15, quad = lane >> 4;
    const int wt = wave * 32;                 // wave owns 32 tokens
    const int h0 = blockIdx.y * 2;

    for (int h = h0; h < h0 + 2; ++h) {
        const u16* kvh = kvt + (size_t)(bb * 8 + h) * 5120;
        f32x4 acc[5][2] = {};                 // mi: e-tile(80), ni: tok-tile(32)
#pragma unroll
        for (int kc = 0; kc < 2; ++kc) {      // d = kc*32 + quad*8 + j
            bf16x8 bfr[2];
#pragma unroll
            for (int ni = 0; ni < 2; ++ni)
                bfr[ni] = *(const bf16x8*)&qio[(t0 + wt + ni * 16 + frow) * 512 + h * 64 + kc * 32 + quad * 8];
#pragma unroll
            for (int mi = 0; mi < 5; ++mi) {
                bf16x8 afr = *(const bf16x8*)&kvh[(mi * 16 + frow) * 64 + kc * 32 + quad * 8];
#pragma unroll
                for (int ni = 0; ni < 2; ++ni)
                    acc[mi][ni] = __builtin_amdgcn_mfma_f32_16x16x32_bf16(afr, bfr[ni], acc[mi][ni], 0, 0, 0);
            }
        }
#pragma unroll
        for (int ni = 0; ni < 2; ++ni) {
            // den(tok) sits in row e=64: lanes quad==0, reg 0, col=tok&15
            const float den = __shfl(acc[4][ni][0], frow, 64);
            const float z = 1.0f / fmaxf(den, 1e-4f);
            const size_t tok = t0 + wt + ni * 16 + frow;
#pragma unroll
            for (int mi = 0; mi < 4; ++mi) {
                u16x4 o;
#pragma unroll
                for (int reg = 0; reg < 4; ++reg) o[reg] = f2bf(acc[mi][ni][reg] * z);
                *(u16x4*)&qio[tok * 512 + h * 64 + mi * 16 + quad * 4] = o;
            }
        }
    }
}

// ---------------------------------------------------------------------------
// gemm_out: out[t][c] (fp32) = sum_i attn[t][i]*Wout[c][i] + bias[c].
// All-bf16 inputs, global_load_lds staging.
// ---------------------------------------------------------------------------
__global__ __launch_bounds__(256) void gemm_out(const u16* __restrict__ A,
                                                const u16* __restrict__ Bw,
                                                float* __restrict__ C,
                                                const float* __restrict__ bias)
{
    __shared__ u16 As[128 * 32];
    __shared__ u16 Bs[128 * 32];
    const int tid  = threadIdx.x;
    const int wave = tid >> 6, lane = tid & 63;
    const size_t row0 = (size_t)blockIdx.x * 128;
    const int    col0 = blockIdx.y * 128;
    const int wr = (wave >> 1) * 64, wc = (wave & 1) * 64;
    const int frow = lane & 15, quad = lane >> 4;

    f32x4 acc[4][4] = {};

    const int ch0 = wave * 64 + lane, ch1 = 256 + ch0;
    const int r0 = ch0 >> 2, c0 = (ch0 & 3) * 8;
    const int r1 = ch1 >> 2, c1 = (ch1 & 3) * 8;
    const u16* gA0 = A + (row0 + r0) * 512 + c0;
    const u16* gA1 = A + (row0 + r1) * 512 + c1;
    const u16* gB0 = Bw + (size_t)(col0 + r0) * 512 + c0;
    const u16* gB1 = Bw + (size_t)(col0 + r1) * 512 + c1;
    u16* lA0 = As + wave * 512;  u16* lA1 = As + 2048 + wave * 512;
    u16* lB0 = Bs + wave * 512;  u16* lB1 = Bs + 2048 + wave * 512;

    for (int k0 = 0; k0 < 512; k0 += 32) {
        __syncthreads();
        gld16(gA0 + k0, lA0); gld16(gA1 + k0, lA1);
        gld16(gB0 + k0, lB0); gld16(gB1 + k0, lB1);
        __syncthreads();

        bf16x8 af[4], bfr[4];
#pragma unroll
        for (int mi = 0; mi < 4; ++mi)
            af[mi] = *(const bf16x8*)&As[(wr + mi * 16 + frow) * 32 + quad * 8];
#pragma unroll
        for (int ni = 0; ni < 4; ++ni)
            bfr[ni] = *(const bf16x8*)&Bs[(wc + ni * 16 + frow) * 32 + quad * 8];
#pragma unroll
        for (int mi = 0; mi < 4; ++mi)
#pragma unroll
            for (int ni = 0; ni < 4; ++ni)
                acc[mi][ni] = __builtin_amdgcn_mfma_f32_16x16x32_bf16(af[mi], bfr[ni], acc[mi][ni], 0, 0, 0);
    }

#pragma unroll
    for (int mi = 0; mi < 4; ++mi) {
#pragma unroll
        for (int ni = 0; ni < 4; ++ni) {
            const int c = col0 + wc + ni * 16 + frow;
            const float bv = bias[c];
            const size_t rbase = row0 + wr + mi * 16 + quad * 4;
#pragma unroll
            for (int reg = 0; reg < 4; ++reg)
                C[(rbase + reg) * 512 + c] = acc[mi][ni][reg] + bv;
        }
    }
}

extern "C" void kernel_launch(void* const* d_in, const int* in_sizes, int n_in,
                              void* d_out, int out_size, void* d_ws, size_t ws_size,
                              hipStream_t stream)
{
    const float* x    = (const float*)d_in[0];   // [65536, 512] fp32
    const float* Wqkv = (const float*)d_in[1];   // [1536, 512]  fp32
    const float* Wout = (const float*)d_in[2];   // [512, 512]   fp32
    const float* bout = (const float*)d_in[3];   // [512]        fp32
    float* out = (float*)d_out;                  // [65536, 512] fp32
    char* ws = (char*)d_ws;

    u16*   wq_bf  = (u16*)ws;                      //   1,572,864 B
    u16*   wo_bf  = (u16*)(ws + 1572864ull);       //     524,288 B
    u16*   wsq    = (u16*)(ws + 2097152ull);       //  67,108,864 B
    u16*   xb     = (u16*)(ws + 69206016ull);      //  67,108,864 B
    float* kvglob = (float*)(ws + 136314880ull);   //   2,621,440 B
    u16*   kvt    = (u16*)(ws + 138936320ull);     //   1,310,720 B -> 140,247,040

    // 0) x -> bf16, weights -> bf16, zero kv accumulator (one kernel)
    convert_all<<<17216, 256, 0, stream>>>(x, Wqkv, Wout, xb, wq_bf, wo_bf, kvglob);
    // 1) q' = act(xb @ Wq^T) -> wsq (bf16)
    gemm_q<<<dim3(512, 4), 256, 0, stream>>>(xb, wq_bf, wsq);
    // 2) per-(head, token-tile) k/v GEMM + kv outer-product partials
    kv_head<<<dim3(8, 512), 256, 0, stream>>>(xb, wq_bf, kvglob);
    // 3) transpose -> bf16 kvt (row e=64 = ksum)
    reduce_kvt<<<128, 256, 0, stream>>>(kvglob, kvt);
    // 4) attention apply, in-place on wsq (q' -> attn), 2 heads per block
    apply_attn<<<dim3(512, 4), 256, 0, stream>>>(wsq, kvt);
    // 5) out = attn @ Wout^T + b_out -> d_out (fp32)
    gemm_out<<<dim3(512, 4), 256, 0, stream>>>(wsq, wo_bf, out, bout);
}

// Round 3
// 490.141 us; speedup vs baseline: 1.2591x; 1.1366x over previous
//
#include <hip/hip_runtime.h>

// LinearAttention: b=16, n=4096, dim=512, H=8, D=64, inner=512. T=65536 tokens.
// I/O dtype: fp32 (per reference). Compute: bf16 MFMA, fp32 accumulate.
// ws layout (~133.8 MiB):
//   wq_bf  [1536x512 bf16]  W_qkv converted + ROW-PERMUTED:
//            rows 0..511 = q; rows 512+h*128+[0..63] = k of head h;
//            rows 512+h*128+[64..127] = v of head h.
//   wo_bf  [ 512x512 bf16]  converted W_out
//   wsq    [65536x512 bf16] q' = act(x@Wq^T); overwritten in-place with attn
//   xb     [65536x512 bf16] x converted once
//   kvglob [128 x 64x80 f32] kv accumulator (atomicAdd), col e=64 = ksum
//   kvt    [128 x 80x64 bf16] kv transposed [e][d]; row 64 = ksum

typedef unsigned short u16;
typedef u16 u16x4 __attribute__((ext_vector_type(4)));
typedef u16 u16x8 __attribute__((ext_vector_type(8)));
typedef __bf16 bf16x8 __attribute__((ext_vector_type(8)));
typedef float f32x4 __attribute__((ext_vector_type(4)));

__device__ __forceinline__ u16 f2bf(float f) {
    union { float f; unsigned u; } t; t.f = f;
    unsigned r = t.u + 0x7fffu + ((t.u >> 16) & 1u);   // RNE
    return (u16)(r >> 16);
}
__device__ __forceinline__ float act_fn(float v) {     // 1 + elu
    return v > 0.0f ? v + 1.0f : __expf(v);
}
__device__ __forceinline__ void cvt8(const float* __restrict__ s, u16* __restrict__ d) {
    f32x4 lo = *(const f32x4*)s;
    f32x4 hi = *(const f32x4*)(s + 4);
    u16x8 o = { f2bf(lo[0]), f2bf(lo[1]), f2bf(lo[2]), f2bf(lo[3]),
                f2bf(hi[0]), f2bf(hi[1]), f2bf(hi[2]), f2bf(hi[3]) };
    *(u16x8*)d = o;
}
// async global->LDS, 16B per lane. LDS dest = wave-uniform base + lane*16.
__device__ __forceinline__ void gld16(const u16* g, u16* l) {
    __builtin_amdgcn_global_load_lds(
        (__attribute__((address_space(1))) const void*)g,
        (__attribute__((address_space(3))) void*)l, 16, 0, 0);
}

// ---------------------------------------------------------------------------
// convert_all: x (4,194,304 x8 units) -> xb ; W_qkv (98,304 units) -> wq_bf
// with the head-interleaved row permutation ; W_out (32,768) -> wo_bf ;
// zero kvglob (81,920 f32 = 10,240 x8 units). 17,216 x 256 exact.
// ---------------------------------------------------------------------------
__global__ __launch_bounds__(256) void convert_all(const float* __restrict__ x,
                                                   const float* __restrict__ Wqkv,
                                                   const float* __restrict__ Wout,
                                                   u16* __restrict__ xb,
                                                   u16* __restrict__ wq,
                                                   u16* __restrict__ wo,
                                                   float* __restrict__ kvg)
{
    size_t u = (size_t)blockIdx.x * 256 + threadIdx.x;
    if (u < 4194304ull) {
        cvt8(x + u * 8, xb + u * 8);
    } else if (u < 4292608ull) {
        u -= 4194304ull;                       // dest unit within wq_bf
        const int drow = (int)(u >> 6);
        int srow;
        if (drow < 512) srow = drow;
        else {
            const int t = drow - 512, h = t >> 7, j = t & 127;
            srow = (j < 64) ? (512 + h * 64 + j) : (1024 + h * 64 + (j - 64));
        }
        cvt8(Wqkv + (size_t)srow * 512 + (u & 63) * 8, wq + u * 8);
    } else if (u < 4325376ull) {
        u -= 4292608ull; cvt8(Wout + u * 8, wo + u * 8);
    } else {
        u -= 4325376ull;
        f32x4 z = { 0.f, 0.f, 0.f, 0.f };
        *(f32x4*)&kvg[u * 8] = z;
        *(f32x4*)&kvg[u * 8 + 4] = z;
    }
}

// ---------------------------------------------------------------------------
// gemm_qkv: C128x128 tile of x @ Wqkv_perm^T, K=512, 2-phase double-buffered
// global_load_lds staging (issue next K-tile before current tile's MFMA).
// Col-tiles 0..3 -> q: act + store to wsq.  Col-tiles 4..11 -> head h=nt-4:
// cols 0..63 = k, 64..127 = v; transpose to KT/VT (overlaying the dead LDS
// double buffer), kv[d][e] += KT@VT^T (VT row 64 = ones -> e=64 = ksum),
// atomicAdd into kvglob[b*8+h].  Grid (12, 512): the 12 blocks sharing an
// x-tile are dispatch-adjacent -> L2/L3-local re-reads.
// ---------------------------------------------------------------------------
__global__ __launch_bounds__(256) void gemm_qkv(const u16* __restrict__ A,
                                                const u16* __restrict__ Bw,
                                                u16* __restrict__ Cq,
                                                float* __restrict__ kvglob)
{
    __shared__ u16 SMF[16384];     // 32 KB: buf b at b*8192 (As 4096 | Bs 4096)
    const int nt = blockIdx.x;     // 0..11 col-tile
    const int mt = blockIdx.y;     // 0..511 M-tile
    const size_t row0 = (size_t)mt * 128;
    const int col0 = nt * 128;
    const int tid = threadIdx.x, wave = tid >> 6, lane = tid & 63;
    const int frow = lane & 15, quad = lane >> 4;
    const int wr = (wave >> 1) * 64, wc = (wave & 1) * 64;

    f32x4 acc[4][4] = {};

    // staging: chunk ch = issue*256 + wave*64 + lane; row = ch>>2, col=(ch&3)*8
    const int ch0 = wave * 64 + lane, ch1 = 256 + ch0;
    const int r0 = ch0 >> 2, c0 = (ch0 & 3) * 8;
    const int r1 = ch1 >> 2, c1 = (ch1 & 3) * 8;
    const u16* gA0 = A + (row0 + r0) * 512 + c0;
    const u16* gA1 = A + (row0 + r1) * 512 + c1;
    const u16* gB0 = Bw + (size_t)(col0 + r0) * 512 + c0;
    const u16* gB1 = Bw + (size_t)(col0 + r1) * 512 + c1;

#define QKV_STAGE(buf, k0) do {                                   \
        u16* As_ = SMF + (buf) * 8192;                            \
        u16* Bs_ = As_ + 4096;                                    \
        gld16(gA0 + (k0), As_ + wave * 512);                      \
        gld16(gA1 + (k0), As_ + 2048 + wave * 512);               \
        gld16(gB0 + (k0), Bs_ + wave * 512);                      \
        gld16(gB1 + (k0), Bs_ + 2048 + wave * 512);               \
    } while (0)

    QKV_STAGE(0, 0);
    __syncthreads();               // implicit vmcnt(0): buf0 ready
    int cur = 0;
    for (int t = 0; t < 16; ++t) {
        if (t < 15) QKV_STAGE(cur ^ 1, (t + 1) * 32);   // prefetch next tile
        const u16* As_ = SMF + cur * 8192;
        const u16* Bs_ = As_ + 4096;
        bf16x8 af[4], bfr[4];
#pragma unroll
        for (int mi = 0; mi < 4; ++mi)
            af[mi] = *(const bf16x8*)&As_[(wr + mi * 16 + frow) * 32 + quad * 8];
#pragma unroll
        for (int ni = 0; ni < 4; ++ni)
            bfr[ni] = *(const bf16x8*)&Bs_[(wc + ni * 16 + frow) * 32 + quad * 8];
#pragma unroll
        for (int mi = 0; mi < 4; ++mi)
#pragma unroll
            for (int ni = 0; ni < 4; ++ni)
                acc[mi][ni] = __builtin_amdgcn_mfma_f32_16x16x32_bf16(af[mi], bfr[ni], acc[mi][ni], 0, 0, 0);
        __syncthreads();           // drains vmcnt(0): prefetched buf ready
        cur ^= 1;
    }
#undef QKV_STAGE

    if (col0 < 512) {
        // q epilogue: C/D layout col = lane&15, row = quad*4 + reg [m89/m91]
#pragma unroll
        for (int mi = 0; mi < 4; ++mi) {
#pragma unroll
            for (int ni = 0; ni < 4; ++ni) {
                const int c = col0 + wc + ni * 16 + frow;
                const size_t rbase = row0 + wr + mi * 16 + quad * 4;
#pragma unroll
                for (int reg = 0; reg < 4; ++reg)
                    Cq[(rbase + reg) * 512 + c] = f2bf(act_fn(acc[mi][ni][reg]));
            }
        }
        return;
    }

    // ---- kv epilogue (head h = nt-4), KT/VT overlay the dead double buffer
    u16* KT = SMF;                 // [64][72] k^T
    u16* VT = SMF + 4608;          // [80][72] v^T; row 64 = ones
    for (int i = tid; i < 16 * 72; i += 256)
        VT[64 * 72 + i] = (i < 64) ? (u16)0x3F80 : (u16)0;

    const bool is_k = (wc == 0);
    f32x4 kvacc[5] = {};           // e-tiles; d = wave*16 + quad*4 + reg

#pragma unroll
    for (int half = 0; half < 2; ++half) {
        __syncthreads();           // prior KT/VT readers (and ones writes) done
        if ((wave >> 1) == half) { // this wave's tokens belong to this half
#pragma unroll
            for (int mi = 0; mi < 4; ++mi) {
                const int n0 = wr + mi * 16 + quad * 4 - half * 64;   // 0..60
#pragma unroll
                for (int ni = 0; ni < 4; ++ni) {
                    const int cl = wc + ni * 16 + frow;               // 0..127
                    u16x4 o;
#pragma unroll
                    for (int reg = 0; reg < 4; ++reg) {
                        float v = acc[mi][ni][reg];
                        if (is_k) v = act_fn(v);
                        o[reg] = f2bf(v);
                    }
                    if (is_k) *(u16x4*)&KT[cl * 72 + n0] = o;
                    else      *(u16x4*)&VT[(cl - 64) * 72 + n0] = o;
                }
            }
        }
        __syncthreads();
        // kv[d][e] += KT@VT^T over this half's 64 tokens (2 K-chunks of 32)
#pragma unroll
        for (int c = 0; c < 2; ++c) {
            bf16x8 af2 = *(const bf16x8*)&KT[(wave * 16 + frow) * 72 + c * 32 + quad * 8];
#pragma unroll
            for (int et = 0; et < 5; ++et) {
                bf16x8 bf2 = *(const bf16x8*)&VT[(et * 16 + frow) * 72 + c * 32 + quad * 8];
                kvacc[et] = __builtin_amdgcn_mfma_f32_16x16x32_bf16(af2, bf2, kvacc[et], 0, 0, 0);
            }
        }
    }

    const int b = mt >> 5, h = nt - 4;
    float* dst = kvglob + (size_t)(b * 8 + h) * 5120;
#pragma unroll
    for (int et = 0; et < 5; ++et) {
        const int e = et * 16 + frow;
        if (e <= 64) {
#pragma unroll
            for (int reg = 0; reg < 4; ++reg) {
                const int d = wave * 16 + quad * 4 + reg;
                atomicAdd(&dst[d * 80 + e], kvacc[et][reg]);
            }
        }
    }
}

// kvt[bh][e][d] bf16: transpose of kvglob[bh][d][e]; e rows 65..79 zero.
__global__ __launch_bounds__(256) void reduce_kvt(const float* __restrict__ kvglob,
                                                  u16* __restrict__ kvt)
{
    const int bh = blockIdx.x, tid = threadIdx.x;
    for (int i = tid; i < 5120; i += 256) {
        const int e = i >> 6, d = i & 63;
        kvt[(size_t)bh * 5120 + i] =
            (e < 65) ? f2bf(kvglob[(size_t)bh * 5120 + d * 80 + e]) : (u16)0;
    }
}

// ---------------------------------------------------------------------------
// apply_attn: attnT[e][tok] = sum_d kvt[e][d] * q'[tok][d] by MFMA; row e=64
// gives denominator (shfl-broadcast); attn = num*z overwrites q' IN PLACE.
// Grid (512 token-blocks x 4 head-pairs). In-place safe: blocks touch
// disjoint (token, col) regions; per head, reads precede writes in-wave.
// ---------------------------------------------------------------------------
__global__ __launch_bounds__(256) void apply_attn(u16* __restrict__ qio,
                                                  const u16* __restrict__ kvt)
{
    const int blk = blockIdx.x;               // 512 blocks x 128 tokens
    const size_t t0 = (size_t)blk * 128;
    const int bb = blk >> 5;                  // batch = 32 blocks
    const int tid = threadIdx.x, wave = tid >> 6, lane = tid & 63;
    const int frow = lane & 15, quad = lane >> 4;
    const int wt = wave * 32;                 // wave owns 32 tokens
    const int h0 = blockIdx.y * 2;

    for (int h = h0; h < h0 + 2; ++h) {
        const u16* kvh = kvt + (size_t)(bb * 8 + h) * 5120;
        f32x4 acc[5][2] = {};                 // mi: e-tile(80), ni: tok-tile(32)
#pragma unroll
        for (int kc = 0; kc < 2; ++kc) {      // d = kc*32 + quad*8 + j
            bf16x8 bfr[2];
#pragma unroll
            for (int ni = 0; ni < 2; ++ni)
                bfr[ni] = *(const bf16x8*)&qio[(t0 + wt + ni * 16 + frow) * 512 + h * 64 + kc * 32 + quad * 8];
#pragma unroll
            for (int mi = 0; mi < 5; ++mi) {
                bf16x8 afr = *(const bf16x8*)&kvh[(mi * 16 + frow) * 64 + kc * 32 + quad * 8];
#pragma unroll
                for (int ni = 0; ni < 2; ++ni)
                    acc[mi][ni] = __builtin_amdgcn_mfma_f32_16x16x32_bf16(afr, bfr[ni], acc[mi][ni], 0, 0, 0);
            }
        }
#pragma unroll
        for (int ni = 0; ni < 2; ++ni) {
            // den(tok) sits in row e=64: lanes quad==0, reg 0, col=tok&15
            const float den = __shfl(acc[4][ni][0], frow, 64);
            const float z = 1.0f / fmaxf(den, 1e-4f);
            const size_t tok = t0 + wt + ni * 16 + frow;
#pragma unroll
            for (int mi = 0; mi < 4; ++mi) {
                u16x4 o;
#pragma unroll
                for (int reg = 0; reg < 4; ++reg) o[reg] = f2bf(acc[mi][ni][reg] * z);
                *(u16x4*)&qio[tok * 512 + h * 64 + mi * 16 + quad * 4] = o;
            }
        }
    }
}

// ---------------------------------------------------------------------------
// gemm_out: out[t][c] (fp32) = sum_i attn[t][i]*Wout[c][i] + bias[c].
// All-bf16 inputs, 2-phase double-buffered global_load_lds staging.
// Grid (4, 512): blocks sharing an A-tile are dispatch-adjacent.
// ---------------------------------------------------------------------------
__global__ __launch_bounds__(256) void gemm_out(const u16* __restrict__ A,
                                                const u16* __restrict__ Bw,
                                                float* __restrict__ C,
                                                const float* __restrict__ bias)
{
    __shared__ u16 SMF[16384];
    const int nt = blockIdx.x;     // 0..3 col-tile
    const int mt = blockIdx.y;     // 0..511 M-tile
    const size_t row0 = (size_t)mt * 128;
    const int col0 = nt * 128;
    const int tid  = threadIdx.x;
    const int wave = tid >> 6, lane = tid & 63;
    const int wr = (wave >> 1) * 64, wc = (wave & 1) * 64;
    const int frow = lane & 15, quad = lane >> 4;

    f32x4 acc[4][4] = {};

    const int ch0 = wave * 64 + lane, ch1 = 256 + ch0;
    const int r0 = ch0 >> 2, c0 = (ch0 & 3) * 8;
    const int r1 = ch1 >> 2, c1 = (ch1 & 3) * 8;
    const u16* gA0 = A + (row0 + r0) * 512 + c0;
    const u16* gA1 = A + (row0 + r1) * 512 + c1;
    const u16* gB0 = Bw + (size_t)(col0 + r0) * 512 + c0;
    const u16* gB1 = Bw + (size_t)(col0 + r1) * 512 + c1;

#define OUT_STAGE(buf, k0) do {                                   \
        u16* As_ = SMF + (buf) * 8192;                            \
        u16* Bs_ = As_ + 4096;                                    \
        gld16(gA0 + (k0), As_ + wave * 512);                      \
        gld16(gA1 + (k0), As_ + 2048 + wave * 512);               \
        gld16(gB0 + (k0), Bs_ + wave * 512);                      \
        gld16(gB1 + (k0), Bs_ + 2048 + wave * 512);               \
    } while (0)

    OUT_STAGE(0, 0);
    __syncthreads();
    int cur = 0;
    for (int t = 0; t < 16; ++t) {
        if (t < 15) OUT_STAGE(cur ^ 1, (t + 1) * 32);
        const u16* As_ = SMF + cur * 8192;
        const u16* Bs_ = As_ + 4096;
        bf16x8 af[4], bfr[4];
#pragma unroll
        for (int mi = 0; mi < 4; ++mi)
            af[mi] = *(const bf16x8*)&As_[(wr + mi * 16 + frow) * 32 + quad * 8];
#pragma unroll
        for (int ni = 0; ni < 4; ++ni)
            bfr[ni] = *(const bf16x8*)&Bs_[(wc + ni * 16 + frow) * 32 + quad * 8];
#pragma unroll
        for (int mi = 0; mi < 4; ++mi)
#pragma unroll
            for (int ni = 0; ni < 4; ++ni)
                acc[mi][ni] = __builtin_amdgcn_mfma_f32_16x16x32_bf16(af[mi], bfr[ni], acc[mi][ni], 0, 0, 0);
        __syncthreads();
        cur ^= 1;
    }
#undef OUT_STAGE

#pragma unroll
    for (int mi = 0; mi < 4; ++mi) {
#pragma unroll
        for (int ni = 0; ni < 4; ++ni) {
            const int c = col0 + wc + ni * 16 + frow;
            const float bv = bias[c];
            const size_t rbase = row0 + wr + mi * 16 + quad * 4;
#pragma unroll
            for (int reg = 0; reg < 4; ++reg)
                C[(rbase + reg) * 512 + c] = acc[mi][ni][reg] + bv;
        }
    }
}

extern "C" void kernel_launch(void* const* d_in, const int* in_sizes, int n_in,
                              void* d_out, int out_size, void* d_ws, size_t ws_size,
                              hipStream_t stream)
{
    const float* x    = (const float*)d_in[0];   // [65536, 512] fp32
    const float* Wqkv = (const float*)d_in[1];   // [1536, 512]  fp32
    const float* Wout = (const float*)d_in[2];   // [512, 512]   fp32
    const float* bout = (const float*)d_in[3];   // [512]        fp32
    float* out = (float*)d_out;                  // [65536, 512] fp32
    char* ws = (char*)d_ws;

    u16*   wq_bf  = (u16*)ws;                      //   1,572,864 B
    u16*   wo_bf  = (u16*)(ws + 1572864ull);       //     524,288 B
    u16*   wsq    = (u16*)(ws + 2097152ull);       //  67,108,864 B
    u16*   xb     = (u16*)(ws + 69206016ull);      //  67,108,864 B
    float* kvglob = (float*)(ws + 136314880ull);   //   2,621,440 B
    u16*   kvt    = (u16*)(ws + 138936320ull);     //   1,310,720 B -> 140,247,040

    // 0) x -> bf16, weights -> bf16 (W_qkv row-permuted), zero kv accumulator
    convert_all<<<17216, 256, 0, stream>>>(x, Wqkv, Wout, xb, wq_bf, wo_bf, kvglob);
    // 1) fused qkv GEMM: q -> wsq ; per-head kv outer-product -> kvglob
    gemm_qkv<<<dim3(12, 512), 256, 0, stream>>>(xb, wq_bf, wsq, kvglob);
    // 2) transpose -> bf16 kvt (row e=64 = ksum)
    reduce_kvt<<<128, 256, 0, stream>>>(kvglob, kvt);
    // 3) attention apply, in-place on wsq (q' -> attn), 2 heads per block
    apply_attn<<<dim3(512, 4), 256, 0, stream>>>(wsq, kvt);
    // 4) out = attn @ Wout^T + b_out -> d_out (fp32)
    gemm_out<<<dim3(4, 512), 256, 0, stream>>>(wsq, wo_bf, out, bout);
}